// Round 4
// baseline (14472.438 us; speedup 1.0000x reference)
//
#include <hip/hip_runtime.h>
#include <math.h>

// Problem constants
#define NN 50000
#define GG 2500
// ws layout (float offsets)
#define WS_YG    0
#define WS_SINV  36864
#define WS_FL    (WS_SINV + 19200000)
#define WS_HEL   (WS_FL + 50000)
#define WS_LPEL  (WS_HEL + 50000)
#define WS_SCOV  (WS_LPEL + 50000)
#define WS_TOTAL (WS_SCOV + 2880000)

__device__ __forceinline__ float f4c(const float4& v, int j) {
  // j is always a compile-time constant at call sites (full unroll) ->
  // folds to a plain register access. NEVER take a pointer into a
  // register array (that spills to scratch: R3 post-mortem, 6.8 GB HBM).
  switch (j & 3) {
    case 0: return v.x;
    case 1: return v.y;
    case 2: return v.z;
    default: return v.w;
  }
}

__device__ __forceinline__ void real_sh9(float x, float y, float z, float* o) {
  const float c0 = 0.28209479177387814f;
  const float c1 = 0.4886025119029199f;
  const float ca = 1.0925484305920792f;
  const float c20 = 0.31539156525252005f;
  const float c22 = 0.5462742152960396f;
  o[0] = c0;
  o[1] = c1 * y;
  o[2] = c1 * z;
  o[3] = c1 * x;
  o[4] = ca * x * y;
  o[5] = ca * y * z;
  o[6] = c20 * (3.f * z * z - 1.f);
  o[7] = ca * x * z;
  o[8] = c22 * (x * x - y * y);
}

// Kernel 0: Y_GRID (4096 x 9). Double-precision phase reduction to match
// numpy's float64 cos/sin of the unreduced Fibonacci angle.
__global__ void k_ygrid(float* __restrict__ yg) {
  int i = blockIdx.x * blockDim.x + threadIdx.x;
  if (i >= 4096) return;
  double fr = 0.38196601125010515 * (double)i;  // (3-sqrt5)/2 : ph/(2pi)
  fr -= floor(fr);
  float ph = (float)(fr * 6.283185307179586);
  float z = 1.0f - 2.0f * ((float)i + 0.5f) * (1.0f / 4096.0f);
  float r = sqrtf(fmaxf(1.f - z * z, 0.f));
  float x = r * cosf(ph);
  float y = r * sinf(ph);
  float sh[9];
  real_sh9(x, y, z, sh);
#pragma unroll
  for (int m = 0; m < 9; ++m) yg[i * 9 + m] = sh[m];
}

// Kernel 1 v4: grid (G, 2) o-halves; 320 threads = 20 node-slots x 16 o-threads.
// x read as float4 with one-window ping-pong prefetch (constant-index regs only).
template <int L, int COMP, int OFF>
__device__ __forceinline__ void cov_block(
    const float* __restrict__ s_inter, const float* __restrict__ Wl,
    float b0, float b1, float b2, float b3,
    int n0, int nseg, int gi, int g, int obase,
    float* __restrict__ sinv, float* __restrict__ scov, float* A) {
  const int t = threadIdx.x;
  __syncthreads();  // protect A across l iterations
  // Stage A-half (128 i x 64 o): 2048 float4s across 320 threads.
  for (int q = t; q < 2048; q += 320) {
    const int i = q >> 4;
    const int ol = (q & 15) << 2;
    const float* wp = Wl + i * 512 + obase + ol;
    const float4 w0 = *(const float4*)(wp);
    const float4 w1 = *(const float4*)(wp + 128);
    const float4 w2 = *(const float4*)(wp + 256);
    const float4 w3 = *(const float4*)(wp + 384);
    float4 a;
    a.x = b0 * w0.x + b1 * w1.x + b2 * w2.x + b3 * w3.x;
    a.y = b0 * w0.y + b1 * w1.y + b2 * w2.y + b3 * w3.y;
    a.z = b0 * w0.z + b1 * w1.z + b2 * w2.z + b3 * w3.z;
    a.w = b0 * w0.w + b1 * w1.w + b2 * w2.w + b3 * w3.w;
    *(float4*)(A + i * 64 + ol) = a;
  }
  __syncthreads();
  const int o4 = (t & 15) << 2;   // 4 contiguous local-o per thread
  const int slot = t >> 4;        // 20 node-slots
  if (slot < nseg) {
    const int n = n0 + slot;
    const float4* xv4 = (const float4*)(s_inter + (size_t)n * 1152 + OFF);
    float acc[COMP][4];
#pragma unroll
    for (int m = 0; m < COMP; ++m) {
#pragma unroll
      for (int j = 0; j < 4; ++j) acc[m][j] = 0.f;
    }
    float4 cur[COMP], nxt[COMP];
#pragma unroll
    for (int q = 0; q < COMP; ++q) cur[q] = xv4[q];
    for (int w = 0; w < 32; ++w) {  // 32 windows of 4 i-steps
      const int wn = (w < 31) ? (w + 1) : 31;
#pragma unroll
      for (int q = 0; q < COMP; ++q) nxt[q] = xv4[wn * COMP + q];
#pragma unroll
      for (int di = 0; di < 4; ++di) {
        const float4 a4 = *(const float4*)(A + (w * 4 + di) * 64 + o4);
#pragma unroll
        for (int m = 0; m < COMP; ++m) {
          const int e = di * COMP + m;           // constant after unroll
          const float xs = f4c(cur[e >> 2], e);  // register select, no spill
          acc[m][0] = fmaf(a4.x, xs, acc[m][0]);
          acc[m][1] = fmaf(a4.y, xs, acc[m][1]);
          acc[m][2] = fmaf(a4.z, xs, acc[m][2]);
          acc[m][3] = fmaf(a4.w, xs, acc[m][3]);
        }
      }
#pragma unroll
      for (int q = 0; q < COMP; ++q) cur[q] = nxt[q];
    }
    const bool isf = (n == gi);
    const float invs = 0.044194173824159216f;  // 1/sqrt(512)
#pragma unroll
    for (int j = 0; j < 4; ++j) {
      const int o = obase + o4 + j;
      float s = 1e-12f;
#pragma unroll
      for (int m = 0; m < COMP; ++m) {
        const float cv = acc[m][j] * invs;
        s += cv * cv;
        if (isf) scov[(size_t)g * 1152 + OFF + o * COMP + m] = cv;
      }
      sinv[(size_t)n * 384 + L * 128 + o] = sqrtf(s);
    }
  }
}

__global__ __launch_bounds__(320) void k_cov(
    const float* __restrict__ s_inter, const float* __restrict__ bag,
    const int* __restrict__ ptr, const int* __restrict__ focus,
    const float* __restrict__ W_bag,
    float* __restrict__ sinv, float* __restrict__ scov) {
  __shared__ __align__(16) float A[8192];  // 32 KB
  const int g = blockIdx.x;
  const int obase = blockIdx.y * 64;
  const int n0 = ptr[g];
  const int nseg = ptr[g + 1] - n0;
  const int gi = n0 + focus[g];
  const float b0 = bag[g * 4 + 0], b1 = bag[g * 4 + 1];
  const float b2 = bag[g * 4 + 2], b3 = bag[g * 4 + 3];
  cov_block<0, 1, 0>(s_inter, W_bag, b0, b1, b2, b3, n0, nseg, gi, g, obase, sinv, scov, A);
  cov_block<1, 3, 128>(s_inter, W_bag + 65536, b0, b1, b2, b3, n0, nseg, gi, g, obase, sinv, scov, A);
  cov_block<2, 5, 512>(s_inter, W_bag + 131072, b0, b1, b2, b3, n0, nseg, gi, g, obase, sinv, scov, A);
}

// Kernel 2 v3: 16 nodes per 128-thread block; thread t = hidden unit t.
// W1f/W1e column scalars prefetched one 4-step ahead across the whole 384 loop.
__global__ __launch_bounds__(128) void k_mlp(
    const float* __restrict__ sinv, const float* __restrict__ bag,
    const int* __restrict__ batch, const int* __restrict__ element,
    const float* __restrict__ W1f, const float* __restrict__ b1f,
    const float* __restrict__ W2f, const float* __restrict__ b2f,
    const float* __restrict__ W1e, const float* __restrict__ b1e,
    const float* __restrict__ W2e, const float* __restrict__ b2e,
    float* __restrict__ flv, float* __restrict__ helv, float* __restrict__ lpelv) {
  __shared__ __align__(16) float lds[4224];  // chunk: [16][64]; later hf/he [16][132] x2
  __shared__ float els[16][4];
  const int t = threadIdx.x;
  const int n0 = blockIdx.x * 16;
  float af[16], ae[16];
#pragma unroll
  for (int p = 0; p < 16; ++p) { af[p] = 0.f; ae[p] = 0.f; }
  const float bf = b1f[t], be = b1e[t];
  float wfc[4], wec[4], wfn[4], wen[4];
#pragma unroll
  for (int j = 0; j < 4; ++j) {
    wfc[j] = W1f[j * 128 + t];
    wec[j] = W1e[j * 128 + t];
  }
  for (int cb = 0; cb < 6; ++cb) {
    const int c0 = cb * 64;
    __syncthreads();
    {
      const int p = t >> 3, q = (t & 7) * 8;
      const float* src = sinv + (size_t)(n0 + p) * 384 + c0 + q;
      const float4 v0 = *(const float4*)(src);
      const float4 v1 = *(const float4*)(src + 4);
      *(float4*)(lds + p * 64 + q) = v0;
      *(float4*)(lds + p * 64 + q + 4) = v1;
    }
    __syncthreads();
    for (int cc = 0; cc < 64; cc += 4) {
      const int cnext = c0 + cc + 4;
      const int cpf = (cnext < 384) ? cnext : 380;
#pragma unroll
      for (int j = 0; j < 4; ++j) {
        wfn[j] = W1f[(cpf + j) * 128 + t];
        wen[j] = W1e[(cpf + j) * 128 + t];
      }
#pragma unroll
      for (int p = 0; p < 16; ++p) {
        const float4 s4 = *(const float4*)(lds + p * 64 + cc);
        af[p] = fmaf(s4.x, wfc[0], af[p]);
        af[p] = fmaf(s4.y, wfc[1], af[p]);
        af[p] = fmaf(s4.z, wfc[2], af[p]);
        af[p] = fmaf(s4.w, wfc[3], af[p]);
        ae[p] = fmaf(s4.x, wec[0], ae[p]);
        ae[p] = fmaf(s4.y, wec[1], ae[p]);
        ae[p] = fmaf(s4.z, wec[2], ae[p]);
        ae[p] = fmaf(s4.w, wec[3], ae[p]);
      }
#pragma unroll
      for (int j = 0; j < 4; ++j) { wfc[j] = wfn[j]; wec[j] = wen[j]; }
    }
  }
  __syncthreads();
#pragma unroll
  for (int p = 0; p < 16; ++p) {
    lds[p * 132 + t] = fmaxf(af[p] + bf, 0.f);          // hf
    lds[2112 + p * 132 + t] = fmaxf(ae[p] + be, 0.f);   // he
  }
  __syncthreads();
  if (t < 80) {  // 16 nodes x (1 fl + 4 el)
    const int p = t / 5, q = t - p * 5;
    if (q == 0) {
      float s = 0.f;
      for (int j = 0; j < 128; ++j) s = fmaf(lds[p * 132 + j], W2f[j], s);
      flv[n0 + p] = s + b2f[0];
    } else {
      const int z = q - 1;
      float s = 0.f;
      for (int j = 0; j < 128; ++j) s = fmaf(lds[2112 + p * 132 + j], W2e[j * 4 + z], s);
      els[p][z] = s + b2e[z];
    }
  }
  __syncthreads();
  if (t < 16) {
    const int n = n0 + t;
    const int g = batch[n];
    const int elem = element[g];
    float v[4];
#pragma unroll
    for (int z = 0; z < 4; ++z) {
      const bool mk = bag[g * 4 + z] > 0.f;
      v[z] = mk ? els[t][z] : -1e9f;
    }
    const float mx = fmaxf(fmaxf(v[0], v[1]), fmaxf(v[2], v[3]));
    float e[4];
    float S = 0.f;
#pragma unroll
    for (int z = 0; z < 4; ++z) { e[z] = expf(v[z] - mx); S += e[z]; }
    const float iS = 1.f / S;
    float h = 0.f;
#pragma unroll
    for (int z = 0; z < 4; ++z) {
      const float pz = e[z] * iS;
      h -= pz * logf(fmaxf(pz, 1e-20f));
    }
    helv[n] = h;
    lpelv[n] = logf(e[elem] * iS + 1e-20f);
  }
}

// Kernel 3: per-group epilogue.
__global__ __launch_bounds__(128) void k_group(
    const int* __restrict__ ptr, const int* __restrict__ focus,
    const int* __restrict__ element, const float* __restrict__ distance,
    const float* __restrict__ orientation, const float* __restrict__ dls,
    const float* __restrict__ W_mix,
    const float* __restrict__ W1d, const float* __restrict__ b1d,
    const float* __restrict__ W2d, const float* __restrict__ b2d,
    const float* __restrict__ flv, const float* __restrict__ helv,
    const float* __restrict__ lpelv, const float* __restrict__ sinv,
    const float* __restrict__ scov, const float* __restrict__ yg,
    float* __restrict__ out) {
  __shared__ float fls[32];
  __shared__ float hels[32];
  __shared__ __align__(16) float svg[384];
  __shared__ float hd[128];
  __shared__ float out6[6];
  __shared__ float red[128][12];
  __shared__ float conds[9];
  __shared__ float mred[128];
  __shared__ float sred[128];
  const int g = blockIdx.x;
  const int t = threadIdx.x;
  const int n0 = ptr[g];
  const int nseg = ptr[g + 1] - n0;
  const int floc = focus[g];
  const int gi = n0 + floc;
  const int elem = element[g];
  const float dist = distance[g];
  if (t < nseg) { fls[t] = flv[n0 + t]; hels[t] = helv[n0 + t]; }
  for (int c = t; c < 384; c += 128) svg[c] = sinv[(size_t)gi * 384 + c];
  __syncthreads();
  float res_lpf = 0.f, res_ent = 0.f;
  if (t == 0) {  // focus softmax + entropies (20-long serial)
    float mx = -1e30f;
    for (int p = 0; p < nseg; ++p) mx = fmaxf(mx, fls[p]);
    float S = 0.f;
    for (int p = 0; p < nseg; ++p) S += expf(fls[p] - mx);
    const float iS = 1.f / S;
    float hfoc = 0.f, hef = 0.f;
    for (int p = 0; p < nseg; ++p) {
      const float pp = expf(fls[p] - mx) * iS;
      hfoc -= pp * logf(pp + 1e-20f);
      hef += pp * hels[p];
    }
    res_lpf = logf(expf(fls[floc] - mx) * iS + 1e-20f);
    res_ent = hfoc + hef;
  }
  // d-MLP hidden: thread t = hidden unit
  {
    float acc = b1d[t];
    for (int c = 0; c < 384; c += 4) {
      const float4 s4 = *(const float4*)(&svg[c]);
      acc = fmaf(s4.x, W1d[(c + 0) * 128 + t], acc);
      acc = fmaf(s4.y, W1d[(c + 1) * 128 + t], acc);
      acc = fmaf(s4.z, W1d[(c + 2) * 128 + t], acc);
      acc = fmaf(s4.w, W1d[(c + 3) * 128 + t], acc);
    }
    acc += W1d[(384 + elem) * 128 + t];  // one-hot element tail
    hd[t] = fmaxf(acc, 0.f);
  }
  __syncthreads();
  if (t < 6) {
    float s = 0.f;
    for (int j = 0; j < 128; ++j) s = fmaf(hd[j], W2d[j * 6 + t], s);
    out6[t] = s + b2d[t];
  }
  // Bessel mix + conditional cov partials (thread t = i index)
  {
    float bess[8];
    const float sq2d = 1.0540925533894598f;  // sqrt(2/1.8)
#pragma unroll
    for (int k = 0; k < 8; ++k)
      bess[k] = sq2d * sinf((float)(k + 1) * 3.14159265358979323846f * dist / 1.8f) / dist;
    const float invnb = 0.35355339059327373f;  // 1/sqrt(8)
    float partial[9];
    {
      float tw = 0.f;
#pragma unroll
      for (int k = 0; k < 8; ++k) tw += bess[k] * W_mix[k * 1536 + t * 4 + elem];
      tw *= invnb;
      partial[0] = scov[(size_t)g * 1152 + t] * tw;
    }
    {
      float tw = 0.f;
#pragma unroll
      for (int k = 0; k < 8; ++k) tw += bess[k] * W_mix[k * 1536 + (128 + t) * 4 + elem];
      tw *= invnb;
#pragma unroll
      for (int m = 0; m < 3; ++m) partial[1 + m] = scov[(size_t)g * 1152 + 128 + t * 3 + m] * tw;
    }
    {
      float tw = 0.f;
#pragma unroll
      for (int k = 0; k < 8; ++k) tw += bess[k] * W_mix[k * 1536 + (256 + t) * 4 + elem];
      tw *= invnb;
#pragma unroll
      for (int m = 0; m < 5; ++m) partial[4 + m] = scov[(size_t)g * 1152 + 512 + t * 5 + m] * tw;
    }
#pragma unroll
    for (int q = 0; q < 9; ++q) red[t][q] = partial[q];
  }
  __syncthreads();
  if (t < 9) {
    float s = 0.f;
    for (int i = 0; i < 128; ++i) s += red[i][t];
    conds[t] = s * 0.044194173824159216f;  // /sqrt(512)
  }
  __syncthreads();
  const float c0 = conds[0], c1 = conds[1], c2 = conds[2], c3 = conds[3];
  const float c4 = conds[4], c5 = conds[5], c6 = conds[6], c7 = conds[7];
  const float c8 = conds[8];
  // spherical logsumexp over 4096 grid points (online per thread)
  float lm = -1e30f, ls = 0.f;
  for (int p = t; p < 4096; p += 128) {
    const float* yp = yg + p * 9;
    float v = c0 * yp[0] + c1 * yp[1] + c2 * yp[2] + c3 * yp[3] + c4 * yp[4] +
              c5 * yp[5] + c6 * yp[6] + c7 * yp[7] + c8 * yp[8];
    v *= 10.0f;
    if (v > lm) { ls = ls * expf(lm - v) + 1.f; lm = v; }
    else ls += expf(v - lm);
  }
  mred[t] = lm;
  sred[t] = ls;
  __syncthreads();
  if (t == 0) {
    // distance GMM
    const float l0 = out6[0], l1 = out6[1], l2 = out6[2];
    const float lmx = fmaxf(l0, fmaxf(l1, l2));
    const float lsew = lmx + logf(expf(l0 - lmx) + expf(l1 - lmx) + expf(l2 - lmx));
    float vals[3];
#pragma unroll
    for (int k = 0; k < 3; ++k) {
      const float mean = tanhf(out6[3 + k]) * 0.45f + 1.35f;
      const float sd = fmaxf(expf(dls[k]), 1e-6f);
      const float zz = (dist - mean) / sd;
      vals[k] = (out6[k] - lsew) + (-0.5f * zz * zz - logf(sd) - 0.9189385332046727f);
    }
    const float vm = fmaxf(vals[0], fmaxf(vals[1], vals[2]));
    const float lp_dist =
        vm + logf(expf(vals[0] - vm) + expf(vals[1] - vm) + expf(vals[2] - vm));
    // merge grid lse
    float Mx = -1e30f;
    for (int i = 0; i < 128; ++i) Mx = fmaxf(Mx, mred[i]);
    float S = 0.f;
    for (int i = 0; i < 128; ++i) S += sred[i] * expf(mred[i] - Mx);
    const float logZ = Mx + logf(S) - 8.317766166719343f + 2.5310242469692907f;
    // orientation term
    float ox = orientation[g * 3 + 0], oy = orientation[g * 3 + 1], oz = orientation[g * 3 + 2];
    const float inr = 1.f / sqrtf(ox * ox + oy * oy + oz * oz);
    ox *= inr; oy *= inr; oz *= inr;
    float sh[9];
    real_sh9(ox, oy, oz, sh);
    const float fx = c0 * sh[0] + c1 * sh[1] + c2 * sh[2] + c3 * sh[3] + c4 * sh[4] +
                     c5 * sh[5] + c6 * sh[6] + c7 * sh[7] + c8 * sh[8];
    const float lp_ori = 10.0f * fx - logZ;
    out[g * 2 + 0] = res_lpf + lpelv[gi] + lp_dist + lp_ori;
    out[g * 2 + 1] = res_ent;
  }
}

extern "C" void kernel_launch(void* const* d_in, const int* in_sizes, int n_in,
                              void* d_out, int out_size, void* d_ws, size_t ws_size,
                              hipStream_t stream) {
  const float* s_inter = (const float*)d_in[0];
  const float* bag = (const float*)d_in[1];
  const int* batch = (const int*)d_in[2];
  const int* ptr = (const int*)d_in[3];
  const int* focus = (const int*)d_in[4];
  const int* element = (const int*)d_in[5];
  const float* distance = (const float*)d_in[6];
  const float* orientation = (const float*)d_in[7];
  const float* W_bag = (const float*)d_in[8];
  const float* dls = (const float*)d_in[9];
  const float* W_mix = (const float*)d_in[10];
  const float* W1f = (const float*)d_in[11];
  const float* b1f = (const float*)d_in[12];
  const float* W2f = (const float*)d_in[13];
  const float* b2f = (const float*)d_in[14];
  const float* W1e = (const float*)d_in[15];
  const float* b1e = (const float*)d_in[16];
  const float* W2e = (const float*)d_in[17];
  const float* b2e = (const float*)d_in[18];
  const float* W1d = (const float*)d_in[19];
  const float* b1d = (const float*)d_in[20];
  const float* W2d = (const float*)d_in[21];
  const float* b2d = (const float*)d_in[22];

  if (ws_size < (size_t)WS_TOTAL * sizeof(float)) return;  // need ~89 MB scratch

  float* ws = (float*)d_ws;
  float* yg = ws + WS_YG;
  float* sinv = ws + WS_SINV;
  float* flv = ws + WS_FL;
  float* helv = ws + WS_HEL;
  float* lpelv = ws + WS_LPEL;
  float* scov = ws + WS_SCOV;
  float* out = (float*)d_out;

  k_ygrid<<<dim3(32), dim3(128), 0, stream>>>(yg);
  k_cov<<<dim3(GG, 2), dim3(320), 0, stream>>>(s_inter, bag, ptr, focus, W_bag, sinv, scov);
  k_mlp<<<dim3(NN / 16), dim3(128), 0, stream>>>(sinv, bag, batch, element,
                                                 W1f, b1f, W2f, b2f,
                                                 W1e, b1e, W2e, b2e,
                                                 flv, helv, lpelv);
  k_group<<<dim3(GG), dim3(128), 0, stream>>>(ptr, focus, element, distance, orientation,
                                              dls, W_mix, W1d, b1d, W2d, b2d,
                                              flv, helv, lpelv, sinv, scov, yg, out);
}

// Round 5
// 4032.627 us; speedup vs baseline: 3.5888x; 3.5888x over previous
//
#include <hip/hip_runtime.h>
#include <math.h>

// Problem constants
#define NN 50000
#define GG 2500
// ws layout (float offsets)
#define WS_YG    0
#define WS_SINV  36864
#define WS_FL    (WS_SINV + 19200000)
#define WS_HEL   (WS_FL + 50000)
#define WS_LPEL  (WS_HEL + 50000)
#define WS_SCOV  (WS_LPEL + 50000)
#define WS_TOTAL (WS_SCOV + 2880000)

__device__ __forceinline__ float4 fmaf4(const float4 a, const float s, float4 c) {
  c.x = fmaf(a.x, s, c.x);
  c.y = fmaf(a.y, s, c.y);
  c.z = fmaf(a.z, s, c.z);
  c.w = fmaf(a.w, s, c.w);
  return c;
}

__device__ __forceinline__ void real_sh9(float x, float y, float z, float* o) {
  const float c0 = 0.28209479177387814f;
  const float c1 = 0.4886025119029199f;
  const float ca = 1.0925484305920792f;
  const float c20 = 0.31539156525252005f;
  const float c22 = 0.5462742152960396f;
  o[0] = c0;
  o[1] = c1 * y;
  o[2] = c1 * z;
  o[3] = c1 * x;
  o[4] = ca * x * y;
  o[5] = ca * y * z;
  o[6] = c20 * (3.f * z * z - 1.f);
  o[7] = ca * x * z;
  o[8] = c22 * (x * x - y * y);
}

// Kernel 0: Y_GRID (4096 x 9). Double-precision phase reduction to match
// numpy's float64 cos/sin of the unreduced Fibonacci angle.
__global__ void k_ygrid(float* __restrict__ yg) {
  int i = blockIdx.x * blockDim.x + threadIdx.x;
  if (i >= 4096) return;
  double fr = 0.38196601125010515 * (double)i;  // (3-sqrt5)/2 : ph/(2pi)
  fr -= floor(fr);
  float ph = (float)(fr * 6.283185307179586);
  float z = 1.0f - 2.0f * ((float)i + 0.5f) * (1.0f / 4096.0f);
  float r = sqrtf(fmaxf(1.f - z * z, 0.f));
  float x = r * cosf(ph);
  float y = r * sinf(ph);
  float sh[9];
  real_sh9(x, y, z, sh);
#pragma unroll
  for (int m = 0; m < 9; ++m) yg[i * 9 + m] = sh[m];
}

// ---------------- k_cov v5 ----------------
// grid (G, 2) o-halves; 320 threads = 20 node-slots x 16 o-threads (4 o each).
// Inner loops fully hand-unrolled with NAMED float4 variables only — no
// indexed register arrays (R3/R4 post-mortem: arrays -> scratch spill,
// 35 GB HBM traffic). A staged in LDS (32 KB), x read as named float4s.

__device__ __forceinline__ void stage_A(const float* __restrict__ Wl,
                                        float b0, float b1, float b2, float b3,
                                        int obase, float* __restrict__ A) {
  const int t = threadIdx.x;
  for (int q = t; q < 2048; q += 320) {
    const int i = q >> 4;
    const int ol = (q & 15) << 2;
    const float* wp = Wl + i * 512 + obase + ol;
    const float4 w0 = *(const float4*)(wp);
    const float4 w1 = *(const float4*)(wp + 128);
    const float4 w2 = *(const float4*)(wp + 256);
    const float4 w3 = *(const float4*)(wp + 384);
    float4 a;
    a.x = b0 * w0.x + b1 * w1.x + b2 * w2.x + b3 * w3.x;
    a.y = b0 * w0.y + b1 * w1.y + b2 * w2.y + b3 * w3.y;
    a.z = b0 * w0.z + b1 * w1.z + b2 * w2.z + b3 * w3.z;
    a.w = b0 * w0.w + b1 * w1.w + b2 * w2.w + b3 * w3.w;
    *(float4*)(A + i * 64 + ol) = a;
  }
}

#define INVS 0.044194173824159216f  // 1/sqrt(512)

__device__ __forceinline__ void cov_l0(
    const float* __restrict__ s_inter, const float* __restrict__ Wl,
    float b0, float b1, float b2, float b3,
    int n0, int gi, int g, int obase,
    float* __restrict__ sinv, float* __restrict__ scov, float* __restrict__ A) {
  const int t = threadIdx.x;
  __syncthreads();
  stage_A(Wl, b0, b1, b2, b3, obase, A);
  __syncthreads();
  const int o4 = (t & 15) << 2;
  const int slot = t >> 4;  // always < 20 = nseg
  const int n = n0 + slot;
  const float4* X4 = (const float4*)(s_inter + (size_t)n * 1152);
  float4 acc0 = {0.f, 0.f, 0.f, 0.f};
  for (int w = 0; w < 32; ++w) {
    const float4 xq = X4[w];
    const float* Ab = A + w * 256 + o4;
    const float4 a0 = *(const float4*)(Ab);
    const float4 a1 = *(const float4*)(Ab + 64);
    const float4 a2 = *(const float4*)(Ab + 128);
    const float4 a3 = *(const float4*)(Ab + 192);
    acc0 = fmaf4(a0, xq.x, acc0);
    acc0 = fmaf4(a1, xq.y, acc0);
    acc0 = fmaf4(a2, xq.z, acc0);
    acc0 = fmaf4(a3, xq.w, acc0);
  }
  const bool isf = (n == gi);
#define EPI0(JJ, CMP)                                                  \
  {                                                                    \
    const int o = obase + o4 + JJ;                                     \
    const float cv = acc0.CMP * INVS;                                  \
    if (isf) scov[(size_t)g * 1152 + o] = cv;                          \
    sinv[(size_t)n * 384 + o] = sqrtf(1e-12f + cv * cv);               \
  }
  EPI0(0, x) EPI0(1, y) EPI0(2, z) EPI0(3, w)
#undef EPI0
}

__device__ __forceinline__ void cov_l1(
    const float* __restrict__ s_inter, const float* __restrict__ Wl,
    float b0, float b1, float b2, float b3,
    int n0, int gi, int g, int obase,
    float* __restrict__ sinv, float* __restrict__ scov, float* __restrict__ A) {
  const int t = threadIdx.x;
  __syncthreads();
  stage_A(Wl, b0, b1, b2, b3, obase, A);
  __syncthreads();
  const int o4 = (t & 15) << 2;
  const int slot = t >> 4;
  const int n = n0 + slot;
  const float4* X4 = (const float4*)(s_inter + (size_t)n * 1152 + 128);
  float4 am0 = {0.f, 0.f, 0.f, 0.f};
  float4 am1 = {0.f, 0.f, 0.f, 0.f};
  float4 am2 = {0.f, 0.f, 0.f, 0.f};
  for (int w = 0; w < 32; ++w) {
    const float4 xa = X4[3 * w + 0];
    const float4 xb = X4[3 * w + 1];
    const float4 xc = X4[3 * w + 2];
    const float* Ab = A + w * 256 + o4;
    const float4 a0 = *(const float4*)(Ab);
    const float4 a1 = *(const float4*)(Ab + 64);
    const float4 a2 = *(const float4*)(Ab + 128);
    const float4 a3 = *(const float4*)(Ab + 192);
    am0 = fmaf4(a0, xa.x, am0); am1 = fmaf4(a0, xa.y, am1); am2 = fmaf4(a0, xa.z, am2);
    am0 = fmaf4(a1, xa.w, am0); am1 = fmaf4(a1, xb.x, am1); am2 = fmaf4(a1, xb.y, am2);
    am0 = fmaf4(a2, xb.z, am0); am1 = fmaf4(a2, xb.w, am1); am2 = fmaf4(a2, xc.x, am2);
    am0 = fmaf4(a3, xc.y, am0); am1 = fmaf4(a3, xc.z, am1); am2 = fmaf4(a3, xc.w, am2);
  }
  const bool isf = (n == gi);
#define EPI1(JJ, CMP)                                                          \
  {                                                                            \
    const int o = obase + o4 + JJ;                                             \
    const float c0v = am0.CMP * INVS;                                          \
    const float c1v = am1.CMP * INVS;                                          \
    const float c2v = am2.CMP * INVS;                                          \
    if (isf) {                                                                 \
      float* bp = scov + (size_t)g * 1152 + 128 + o * 3;                       \
      bp[0] = c0v; bp[1] = c1v; bp[2] = c2v;                                   \
    }                                                                          \
    sinv[(size_t)n * 384 + 128 + o] =                                          \
        sqrtf(1e-12f + c0v * c0v + c1v * c1v + c2v * c2v);                     \
  }
  EPI1(0, x) EPI1(1, y) EPI1(2, z) EPI1(3, w)
#undef EPI1
}

__device__ __forceinline__ void cov_l2(
    const float* __restrict__ s_inter, const float* __restrict__ Wl,
    float b0, float b1, float b2, float b3,
    int n0, int gi, int g, int obase,
    float* __restrict__ sinv, float* __restrict__ scov, float* __restrict__ A) {
  const int t = threadIdx.x;
  __syncthreads();
  stage_A(Wl, b0, b1, b2, b3, obase, A);
  __syncthreads();
  const int o4 = (t & 15) << 2;
  const int slot = t >> 4;
  const int n = n0 + slot;
  const float4* X4 = (const float4*)(s_inter + (size_t)n * 1152 + 512);
  float4 am0 = {0.f, 0.f, 0.f, 0.f};
  float4 am1 = {0.f, 0.f, 0.f, 0.f};
  float4 am2 = {0.f, 0.f, 0.f, 0.f};
  float4 am3 = {0.f, 0.f, 0.f, 0.f};
  float4 am4 = {0.f, 0.f, 0.f, 0.f};
  for (int w = 0; w < 32; ++w) {
    const float4 xa = X4[5 * w + 0];
    const float4 xb = X4[5 * w + 1];
    const float4 xc = X4[5 * w + 2];
    const float4 xd = X4[5 * w + 3];
    const float4 xe = X4[5 * w + 4];
    const float* Ab = A + w * 256 + o4;
    const float4 a0 = *(const float4*)(Ab);
    const float4 a1 = *(const float4*)(Ab + 64);
    const float4 a2 = *(const float4*)(Ab + 128);
    const float4 a3 = *(const float4*)(Ab + 192);
    am0 = fmaf4(a0, xa.x, am0); am1 = fmaf4(a0, xa.y, am1); am2 = fmaf4(a0, xa.z, am2);
    am3 = fmaf4(a0, xa.w, am3); am4 = fmaf4(a0, xb.x, am4);
    am0 = fmaf4(a1, xb.y, am0); am1 = fmaf4(a1, xb.z, am1); am2 = fmaf4(a1, xb.w, am2);
    am3 = fmaf4(a1, xc.x, am3); am4 = fmaf4(a1, xc.y, am4);
    am0 = fmaf4(a2, xc.z, am0); am1 = fmaf4(a2, xc.w, am1); am2 = fmaf4(a2, xd.x, am2);
    am3 = fmaf4(a2, xd.y, am3); am4 = fmaf4(a2, xd.z, am4);
    am0 = fmaf4(a3, xd.w, am0); am1 = fmaf4(a3, xe.x, am1); am2 = fmaf4(a3, xe.y, am2);
    am3 = fmaf4(a3, xe.z, am3); am4 = fmaf4(a3, xe.w, am4);
  }
  const bool isf = (n == gi);
#define EPI2(JJ, CMP)                                                          \
  {                                                                            \
    const int o = obase + o4 + JJ;                                             \
    const float c0v = am0.CMP * INVS;                                          \
    const float c1v = am1.CMP * INVS;                                          \
    const float c2v = am2.CMP * INVS;                                          \
    const float c3v = am3.CMP * INVS;                                          \
    const float c4v = am4.CMP * INVS;                                          \
    if (isf) {                                                                 \
      float* bp = scov + (size_t)g * 1152 + 512 + o * 5;                       \
      bp[0] = c0v; bp[1] = c1v; bp[2] = c2v; bp[3] = c3v; bp[4] = c4v;         \
    }                                                                          \
    sinv[(size_t)n * 384 + 256 + o] =                                          \
        sqrtf(1e-12f + c0v * c0v + c1v * c1v + c2v * c2v + c3v * c3v +         \
              c4v * c4v);                                                      \
  }
  EPI2(0, x) EPI2(1, y) EPI2(2, z) EPI2(3, w)
#undef EPI2
}

__global__ __launch_bounds__(320, 4) void k_cov(
    const float* __restrict__ s_inter, const float* __restrict__ bag,
    const int* __restrict__ ptr, const int* __restrict__ focus,
    const float* __restrict__ W_bag,
    float* __restrict__ sinv, float* __restrict__ scov) {
  __shared__ __align__(16) float A[8192];  // 32 KB
  const int g = blockIdx.x;
  const int obase = blockIdx.y * 64;
  const int n0 = ptr[g];
  const int gi = n0 + focus[g];
  const float b0 = bag[g * 4 + 0], b1 = bag[g * 4 + 1];
  const float b2 = bag[g * 4 + 2], b3 = bag[g * 4 + 3];
  cov_l0(s_inter, W_bag, b0, b1, b2, b3, n0, gi, g, obase, sinv, scov, A);
  cov_l1(s_inter, W_bag + 65536, b0, b1, b2, b3, n0, gi, g, obase, sinv, scov, A);
  cov_l2(s_inter, W_bag + 131072, b0, b1, b2, b3, n0, gi, g, obase, sinv, scov, A);
}

// Kernel 2 v3: 16 nodes per 128-thread block; thread t = hidden unit t.
// W1f/W1e column scalars prefetched one 4-step ahead across the whole 384 loop.
__global__ __launch_bounds__(128) void k_mlp(
    const float* __restrict__ sinv, const float* __restrict__ bag,
    const int* __restrict__ batch, const int* __restrict__ element,
    const float* __restrict__ W1f, const float* __restrict__ b1f,
    const float* __restrict__ W2f, const float* __restrict__ b2f,
    const float* __restrict__ W1e, const float* __restrict__ b1e,
    const float* __restrict__ W2e, const float* __restrict__ b2e,
    float* __restrict__ flv, float* __restrict__ helv, float* __restrict__ lpelv) {
  __shared__ __align__(16) float lds[4224];  // chunk: [16][64]; later hf/he [16][132] x2
  __shared__ float els[16][4];
  const int t = threadIdx.x;
  const int n0 = blockIdx.x * 16;
  float af[16], ae[16];
#pragma unroll
  for (int p = 0; p < 16; ++p) { af[p] = 0.f; ae[p] = 0.f; }
  const float bf = b1f[t], be = b1e[t];
  float wfc[4], wec[4], wfn[4], wen[4];
#pragma unroll
  for (int j = 0; j < 4; ++j) {
    wfc[j] = W1f[j * 128 + t];
    wec[j] = W1e[j * 128 + t];
  }
  for (int cb = 0; cb < 6; ++cb) {
    const int c0 = cb * 64;
    __syncthreads();
    {
      const int p = t >> 3, q = (t & 7) * 8;
      const float* src = sinv + (size_t)(n0 + p) * 384 + c0 + q;
      const float4 v0 = *(const float4*)(src);
      const float4 v1 = *(const float4*)(src + 4);
      *(float4*)(lds + p * 64 + q) = v0;
      *(float4*)(lds + p * 64 + q + 4) = v1;
    }
    __syncthreads();
    for (int cc = 0; cc < 64; cc += 4) {
      const int cnext = c0 + cc + 4;
      const int cpf = (cnext < 384) ? cnext : 380;
#pragma unroll
      for (int j = 0; j < 4; ++j) {
        wfn[j] = W1f[(cpf + j) * 128 + t];
        wen[j] = W1e[(cpf + j) * 128 + t];
      }
#pragma unroll
      for (int p = 0; p < 16; ++p) {
        const float4 s4 = *(const float4*)(lds + p * 64 + cc);
        af[p] = fmaf(s4.x, wfc[0], af[p]);
        af[p] = fmaf(s4.y, wfc[1], af[p]);
        af[p] = fmaf(s4.z, wfc[2], af[p]);
        af[p] = fmaf(s4.w, wfc[3], af[p]);
        ae[p] = fmaf(s4.x, wec[0], ae[p]);
        ae[p] = fmaf(s4.y, wec[1], ae[p]);
        ae[p] = fmaf(s4.z, wec[2], ae[p]);
        ae[p] = fmaf(s4.w, wec[3], ae[p]);
      }
#pragma unroll
      for (int j = 0; j < 4; ++j) { wfc[j] = wfn[j]; wec[j] = wen[j]; }
    }
  }
  __syncthreads();
#pragma unroll
  for (int p = 0; p < 16; ++p) {
    lds[p * 132 + t] = fmaxf(af[p] + bf, 0.f);          // hf
    lds[2112 + p * 132 + t] = fmaxf(ae[p] + be, 0.f);   // he
  }
  __syncthreads();
  if (t < 80) {  // 16 nodes x (1 fl + 4 el)
    const int p = t / 5, q = t - p * 5;
    if (q == 0) {
      float s = 0.f;
      for (int j = 0; j < 128; ++j) s = fmaf(lds[p * 132 + j], W2f[j], s);
      flv[n0 + p] = s + b2f[0];
    } else {
      const int z = q - 1;
      float s = 0.f;
      for (int j = 0; j < 128; ++j) s = fmaf(lds[2112 + p * 132 + j], W2e[j * 4 + z], s);
      els[p][z] = s + b2e[z];
    }
  }
  __syncthreads();
  if (t < 16) {
    const int n = n0 + t;
    const int g = batch[n];
    const int elem = element[g];
    float v[4];
#pragma unroll
    for (int z = 0; z < 4; ++z) {
      const bool mk = bag[g * 4 + z] > 0.f;
      v[z] = mk ? els[t][z] : -1e9f;
    }
    const float mx = fmaxf(fmaxf(v[0], v[1]), fmaxf(v[2], v[3]));
    float e[4];
    float S = 0.f;
#pragma unroll
    for (int z = 0; z < 4; ++z) { e[z] = expf(v[z] - mx); S += e[z]; }
    const float iS = 1.f / S;
    float h = 0.f;
#pragma unroll
    for (int z = 0; z < 4; ++z) {
      const float pz = e[z] * iS;
      h -= pz * logf(fmaxf(pz, 1e-20f));
    }
    helv[n] = h;
    lpelv[n] = logf(e[elem] * iS + 1e-20f);
  }
}

// Kernel 3: per-group epilogue.
__global__ __launch_bounds__(128) void k_group(
    const int* __restrict__ ptr, const int* __restrict__ focus,
    const int* __restrict__ element, const float* __restrict__ distance,
    const float* __restrict__ orientation, const float* __restrict__ dls,
    const float* __restrict__ W_mix,
    const float* __restrict__ W1d, const float* __restrict__ b1d,
    const float* __restrict__ W2d, const float* __restrict__ b2d,
    const float* __restrict__ flv, const float* __restrict__ helv,
    const float* __restrict__ lpelv, const float* __restrict__ sinv,
    const float* __restrict__ scov, const float* __restrict__ yg,
    float* __restrict__ out) {
  __shared__ float fls[32];
  __shared__ float hels[32];
  __shared__ __align__(16) float svg[384];
  __shared__ float hd[128];
  __shared__ float out6[6];
  __shared__ float red[128][12];
  __shared__ float conds[9];
  __shared__ float mred[128];
  __shared__ float sred[128];
  const int g = blockIdx.x;
  const int t = threadIdx.x;
  const int n0 = ptr[g];
  const int nseg = ptr[g + 1] - n0;
  const int floc = focus[g];
  const int gi = n0 + floc;
  const int elem = element[g];
  const float dist = distance[g];
  if (t < nseg) { fls[t] = flv[n0 + t]; hels[t] = helv[n0 + t]; }
  for (int c = t; c < 384; c += 128) svg[c] = sinv[(size_t)gi * 384 + c];
  __syncthreads();
  float res_lpf = 0.f, res_ent = 0.f;
  if (t == 0) {  // focus softmax + entropies (20-long serial)
    float mx = -1e30f;
    for (int p = 0; p < nseg; ++p) mx = fmaxf(mx, fls[p]);
    float S = 0.f;
    for (int p = 0; p < nseg; ++p) S += expf(fls[p] - mx);
    const float iS = 1.f / S;
    float hfoc = 0.f, hef = 0.f;
    for (int p = 0; p < nseg; ++p) {
      const float pp = expf(fls[p] - mx) * iS;
      hfoc -= pp * logf(pp + 1e-20f);
      hef += pp * hels[p];
    }
    res_lpf = logf(expf(fls[floc] - mx) * iS + 1e-20f);
    res_ent = hfoc + hef;
  }
  // d-MLP hidden: thread t = hidden unit
  {
    float acc = b1d[t];
    for (int c = 0; c < 384; c += 4) {
      const float4 s4 = *(const float4*)(&svg[c]);
      acc = fmaf(s4.x, W1d[(c + 0) * 128 + t], acc);
      acc = fmaf(s4.y, W1d[(c + 1) * 128 + t], acc);
      acc = fmaf(s4.z, W1d[(c + 2) * 128 + t], acc);
      acc = fmaf(s4.w, W1d[(c + 3) * 128 + t], acc);
    }
    acc += W1d[(384 + elem) * 128 + t];  // one-hot element tail
    hd[t] = fmaxf(acc, 0.f);
  }
  __syncthreads();
  if (t < 6) {
    float s = 0.f;
    for (int j = 0; j < 128; ++j) s = fmaf(hd[j], W2d[j * 6 + t], s);
    out6[t] = s + b2d[t];
  }
  // Bessel mix + conditional cov partials (thread t = i index)
  {
    float bess[8];
    const float sq2d = 1.0540925533894598f;  // sqrt(2/1.8)
#pragma unroll
    for (int k = 0; k < 8; ++k)
      bess[k] = sq2d * sinf((float)(k + 1) * 3.14159265358979323846f * dist / 1.8f) / dist;
    const float invnb = 0.35355339059327373f;  // 1/sqrt(8)
    float partial[9];
    {
      float tw = 0.f;
#pragma unroll
      for (int k = 0; k < 8; ++k) tw += bess[k] * W_mix[k * 1536 + t * 4 + elem];
      tw *= invnb;
      partial[0] = scov[(size_t)g * 1152 + t] * tw;
    }
    {
      float tw = 0.f;
#pragma unroll
      for (int k = 0; k < 8; ++k) tw += bess[k] * W_mix[k * 1536 + (128 + t) * 4 + elem];
      tw *= invnb;
#pragma unroll
      for (int m = 0; m < 3; ++m) partial[1 + m] = scov[(size_t)g * 1152 + 128 + t * 3 + m] * tw;
    }
    {
      float tw = 0.f;
#pragma unroll
      for (int k = 0; k < 8; ++k) tw += bess[k] * W_mix[k * 1536 + (256 + t) * 4 + elem];
      tw *= invnb;
#pragma unroll
      for (int m = 0; m < 5; ++m) partial[4 + m] = scov[(size_t)g * 1152 + 512 + t * 5 + m] * tw;
    }
#pragma unroll
    for (int q = 0; q < 9; ++q) red[t][q] = partial[q];
  }
  __syncthreads();
  if (t < 9) {
    float s = 0.f;
    for (int i = 0; i < 128; ++i) s += red[i][t];
    conds[t] = s * 0.044194173824159216f;  // /sqrt(512)
  }
  __syncthreads();
  const float c0 = conds[0], c1 = conds[1], c2 = conds[2], c3 = conds[3];
  const float c4 = conds[4], c5 = conds[5], c6 = conds[6], c7 = conds[7];
  const float c8 = conds[8];
  // spherical logsumexp over 4096 grid points (online per thread)
  float lm = -1e30f, ls = 0.f;
  for (int p = t; p < 4096; p += 128) {
    const float* yp = yg + p * 9;
    float v = c0 * yp[0] + c1 * yp[1] + c2 * yp[2] + c3 * yp[3] + c4 * yp[4] +
              c5 * yp[5] + c6 * yp[6] + c7 * yp[7] + c8 * yp[8];
    v *= 10.0f;
    if (v > lm) { ls = ls * expf(lm - v) + 1.f; lm = v; }
    else ls += expf(v - lm);
  }
  mred[t] = lm;
  sred[t] = ls;
  __syncthreads();
  if (t == 0) {
    // distance GMM
    const float l0 = out6[0], l1 = out6[1], l2 = out6[2];
    const float lmx = fmaxf(l0, fmaxf(l1, l2));
    const float lsew = lmx + logf(expf(l0 - lmx) + expf(l1 - lmx) + expf(l2 - lmx));
    float vals[3];
#pragma unroll
    for (int k = 0; k < 3; ++k) {
      const float mean = tanhf(out6[3 + k]) * 0.45f + 1.35f;
      const float sd = fmaxf(expf(dls[k]), 1e-6f);
      const float zz = (dist - mean) / sd;
      vals[k] = (out6[k] - lsew) + (-0.5f * zz * zz - logf(sd) - 0.9189385332046727f);
    }
    const float vm = fmaxf(vals[0], fmaxf(vals[1], vals[2]));
    const float lp_dist =
        vm + logf(expf(vals[0] - vm) + expf(vals[1] - vm) + expf(vals[2] - vm));
    // merge grid lse
    float Mx = -1e30f;
    for (int i = 0; i < 128; ++i) Mx = fmaxf(Mx, mred[i]);
    float S = 0.f;
    for (int i = 0; i < 128; ++i) S += sred[i] * expf(mred[i] - Mx);
    const float logZ = Mx + logf(S) - 8.317766166719343f + 2.5310242469692907f;
    // orientation term
    float ox = orientation[g * 3 + 0], oy = orientation[g * 3 + 1], oz = orientation[g * 3 + 2];
    const float inr = 1.f / sqrtf(ox * ox + oy * oy + oz * oz);
    ox *= inr; oy *= inr; oz *= inr;
    float sh[9];
    real_sh9(ox, oy, oz, sh);
    const float fx = c0 * sh[0] + c1 * sh[1] + c2 * sh[2] + c3 * sh[3] + c4 * sh[4] +
                     c5 * sh[5] + c6 * sh[6] + c7 * sh[7] + c8 * sh[8];
    const float lp_ori = 10.0f * fx - logZ;
    out[g * 2 + 0] = res_lpf + lpelv[gi] + lp_dist + lp_ori;
    out[g * 2 + 1] = res_ent;
  }
}

extern "C" void kernel_launch(void* const* d_in, const int* in_sizes, int n_in,
                              void* d_out, int out_size, void* d_ws, size_t ws_size,
                              hipStream_t stream) {
  const float* s_inter = (const float*)d_in[0];
  const float* bag = (const float*)d_in[1];
  const int* batch = (const int*)d_in[2];
  const int* ptr = (const int*)d_in[3];
  const int* focus = (const int*)d_in[4];
  const int* element = (const int*)d_in[5];
  const float* distance = (const float*)d_in[6];
  const float* orientation = (const float*)d_in[7];
  const float* W_bag = (const float*)d_in[8];
  const float* dls = (const float*)d_in[9];
  const float* W_mix = (const float*)d_in[10];
  const float* W1f = (const float*)d_in[11];
  const float* b1f = (const float*)d_in[12];
  const float* W2f = (const float*)d_in[13];
  const float* b2f = (const float*)d_in[14];
  const float* W1e = (const float*)d_in[15];
  const float* b1e = (const float*)d_in[16];
  const float* W2e = (const float*)d_in[17];
  const float* b2e = (const float*)d_in[18];
  const float* W1d = (const float*)d_in[19];
  const float* b1d = (const float*)d_in[20];
  const float* W2d = (const float*)d_in[21];
  const float* b2d = (const float*)d_in[22];

  if (ws_size < (size_t)WS_TOTAL * sizeof(float)) return;  // need ~89 MB scratch

  float* ws = (float*)d_ws;
  float* yg = ws + WS_YG;
  float* sinv = ws + WS_SINV;
  float* flv = ws + WS_FL;
  float* helv = ws + WS_HEL;
  float* lpelv = ws + WS_LPEL;
  float* scov = ws + WS_SCOV;
  float* out = (float*)d_out;

  k_ygrid<<<dim3(32), dim3(128), 0, stream>>>(yg);
  k_cov<<<dim3(GG, 2), dim3(320), 0, stream>>>(s_inter, bag, ptr, focus, W_bag, sinv, scov);
  k_mlp<<<dim3(NN / 16), dim3(128), 0, stream>>>(sinv, bag, batch, element,
                                                 W1f, b1f, W2f, b2f,
                                                 W1e, b1e, W2e, b2e,
                                                 flv, helv, lpelv);
  k_group<<<dim3(GG), dim3(128), 0, stream>>>(ptr, focus, element, distance, orientation,
                                              dls, W_mix, W1d, b1d, W2d, b2d,
                                              flv, helv, lpelv, sinv, scov, yg, out);
}

// Round 6
// 3175.836 us; speedup vs baseline: 4.5570x; 1.2698x over previous
//
#include <hip/hip_runtime.h>
#include <math.h>

// Problem constants
#define NN 50000
#define GG 2500
// ws layout (float offsets)
#define WS_YG    0
#define WS_SINV  36864
#define WS_FL    (WS_SINV + 19200000)
#define WS_HEL   (WS_FL + 50000)
#define WS_LPEL  (WS_HEL + 50000)
#define WS_SCOV  (WS_LPEL + 50000)
#define WS_TOTAL (WS_SCOV + 2880000)

__device__ __forceinline__ float4 fmaf4(const float4 a, const float s, float4 c) {
  c.x = fmaf(a.x, s, c.x);
  c.y = fmaf(a.y, s, c.y);
  c.z = fmaf(a.z, s, c.z);
  c.w = fmaf(a.w, s, c.w);
  return c;
}

__device__ __forceinline__ void real_sh9(float x, float y, float z, float* o) {
  const float c0 = 0.28209479177387814f;
  const float c1 = 0.4886025119029199f;
  const float ca = 1.0925484305920792f;
  const float c20 = 0.31539156525252005f;
  const float c22 = 0.5462742152960396f;
  o[0] = c0;
  o[1] = c1 * y;
  o[2] = c1 * z;
  o[3] = c1 * x;
  o[4] = ca * x * y;
  o[5] = ca * y * z;
  o[6] = c20 * (3.f * z * z - 1.f);
  o[7] = ca * x * z;
  o[8] = c22 * (x * x - y * y);
}

// Kernel 0: Y_GRID (4096 x 9). Double-precision phase reduction to match
// numpy's float64 cos/sin of the unreduced Fibonacci angle.
__global__ void k_ygrid(float* __restrict__ yg) {
  int i = blockIdx.x * blockDim.x + threadIdx.x;
  if (i >= 4096) return;
  double fr = 0.38196601125010515 * (double)i;  // (3-sqrt5)/2 : ph/(2pi)
  fr -= floor(fr);
  float ph = (float)(fr * 6.283185307179586);
  float z = 1.0f - 2.0f * ((float)i + 0.5f) * (1.0f / 4096.0f);
  float r = sqrtf(fmaxf(1.f - z * z, 0.f));
  float x = r * cosf(ph);
  float y = r * sinf(ph);
  float sh[9];
  real_sh9(x, y, z, sh);
#pragma unroll
  for (int m = 0; m < 9; ++m) yg[i * 9 + m] = sh[m];
}

// ---------------- k_cov v6 ----------------
// grid (G, 2) o-halves; 320 threads = 20 node-slots x 16 o-threads (4 o each).
// Named float4 variables only (R3/R4: register arrays spill to scratch).
// Plain __launch_bounds__(320): NO min-waves arg — R5's (320,4) capped the
// allocator at 64 VGPRs and spilled the ~70-reg live set to scratch.

__device__ __forceinline__ void stage_A(const float* __restrict__ Wl,
                                        float b0, float b1, float b2, float b3,
                                        int obase, float* __restrict__ A) {
  const int t = threadIdx.x;
  for (int q = t; q < 2048; q += 320) {
    const int i = q >> 4;
    const int ol = (q & 15) << 2;
    const float* wp = Wl + i * 512 + obase + ol;
    const float4 w0 = *(const float4*)(wp);
    const float4 w1 = *(const float4*)(wp + 128);
    const float4 w2 = *(const float4*)(wp + 256);
    const float4 w3 = *(const float4*)(wp + 384);
    float4 a;
    a.x = b0 * w0.x + b1 * w1.x + b2 * w2.x + b3 * w3.x;
    a.y = b0 * w0.y + b1 * w1.y + b2 * w2.y + b3 * w3.y;
    a.z = b0 * w0.z + b1 * w1.z + b2 * w2.z + b3 * w3.z;
    a.w = b0 * w0.w + b1 * w1.w + b2 * w2.w + b3 * w3.w;
    *(float4*)(A + i * 64 + ol) = a;
  }
}

#define INVS 0.044194173824159216f  // 1/sqrt(512)

__device__ __forceinline__ void cov_l0(
    const float* __restrict__ s_inter, const float* __restrict__ Wl,
    float b0, float b1, float b2, float b3,
    int n0, int gi, int g, int obase,
    float* __restrict__ sinv, float* __restrict__ scov, float* __restrict__ A) {
  const int t = threadIdx.x;
  __syncthreads();
  stage_A(Wl, b0, b1, b2, b3, obase, A);
  __syncthreads();
  const int o4 = (t & 15) << 2;
  const int slot = t >> 4;  // always < 20 = nseg
  const int n = n0 + slot;
  const float4* X4 = (const float4*)(s_inter + (size_t)n * 1152);
  float4 acc0 = {0.f, 0.f, 0.f, 0.f};
  for (int w = 0; w < 32; ++w) {
    const float4 xq = X4[w];
    const float* Ab = A + w * 256 + o4;
    const float4 a0 = *(const float4*)(Ab);
    const float4 a1 = *(const float4*)(Ab + 64);
    const float4 a2 = *(const float4*)(Ab + 128);
    const float4 a3 = *(const float4*)(Ab + 192);
    acc0 = fmaf4(a0, xq.x, acc0);
    acc0 = fmaf4(a1, xq.y, acc0);
    acc0 = fmaf4(a2, xq.z, acc0);
    acc0 = fmaf4(a3, xq.w, acc0);
  }
  const bool isf = (n == gi);
#define EPI0(JJ, CMP)                                                  \
  {                                                                    \
    const int o = obase + o4 + JJ;                                     \
    const float cv = acc0.CMP * INVS;                                  \
    if (isf) scov[(size_t)g * 1152 + o] = cv;                          \
    sinv[(size_t)n * 384 + o] = sqrtf(1e-12f + cv * cv);               \
  }
  EPI0(0, x) EPI0(1, y) EPI0(2, z) EPI0(3, w)
#undef EPI0
}

__device__ __forceinline__ void cov_l1(
    const float* __restrict__ s_inter, const float* __restrict__ Wl,
    float b0, float b1, float b2, float b3,
    int n0, int gi, int g, int obase,
    float* __restrict__ sinv, float* __restrict__ scov, float* __restrict__ A) {
  const int t = threadIdx.x;
  __syncthreads();
  stage_A(Wl, b0, b1, b2, b3, obase, A);
  __syncthreads();
  const int o4 = (t & 15) << 2;
  const int slot = t >> 4;
  const int n = n0 + slot;
  const float4* X4 = (const float4*)(s_inter + (size_t)n * 1152 + 128);
  float4 am0 = {0.f, 0.f, 0.f, 0.f};
  float4 am1 = {0.f, 0.f, 0.f, 0.f};
  float4 am2 = {0.f, 0.f, 0.f, 0.f};
  for (int w = 0; w < 32; ++w) {
    const float4 xa = X4[3 * w + 0];
    const float4 xb = X4[3 * w + 1];
    const float4 xc = X4[3 * w + 2];
    const float* Ab = A + w * 256 + o4;
    const float4 a0 = *(const float4*)(Ab);
    const float4 a1 = *(const float4*)(Ab + 64);
    const float4 a2 = *(const float4*)(Ab + 128);
    const float4 a3 = *(const float4*)(Ab + 192);
    am0 = fmaf4(a0, xa.x, am0); am1 = fmaf4(a0, xa.y, am1); am2 = fmaf4(a0, xa.z, am2);
    am0 = fmaf4(a1, xa.w, am0); am1 = fmaf4(a1, xb.x, am1); am2 = fmaf4(a1, xb.y, am2);
    am0 = fmaf4(a2, xb.z, am0); am1 = fmaf4(a2, xb.w, am1); am2 = fmaf4(a2, xc.x, am2);
    am0 = fmaf4(a3, xc.y, am0); am1 = fmaf4(a3, xc.z, am1); am2 = fmaf4(a3, xc.w, am2);
  }
  const bool isf = (n == gi);
#define EPI1(JJ, CMP)                                                          \
  {                                                                            \
    const int o = obase + o4 + JJ;                                             \
    const float c0v = am0.CMP * INVS;                                          \
    const float c1v = am1.CMP * INVS;                                          \
    const float c2v = am2.CMP * INVS;                                          \
    if (isf) {                                                                 \
      float* bp = scov + (size_t)g * 1152 + 128 + o * 3;                       \
      bp[0] = c0v; bp[1] = c1v; bp[2] = c2v;                                   \
    }                                                                          \
    sinv[(size_t)n * 384 + 128 + o] =                                          \
        sqrtf(1e-12f + c0v * c0v + c1v * c1v + c2v * c2v);                     \
  }
  EPI1(0, x) EPI1(1, y) EPI1(2, z) EPI1(3, w)
#undef EPI1
}

__device__ __forceinline__ void cov_l2(
    const float* __restrict__ s_inter, const float* __restrict__ Wl,
    float b0, float b1, float b2, float b3,
    int n0, int gi, int g, int obase,
    float* __restrict__ sinv, float* __restrict__ scov, float* __restrict__ A) {
  const int t = threadIdx.x;
  __syncthreads();
  stage_A(Wl, b0, b1, b2, b3, obase, A);
  __syncthreads();
  const int o4 = (t & 15) << 2;
  const int slot = t >> 4;
  const int n = n0 + slot;
  const float4* X4 = (const float4*)(s_inter + (size_t)n * 1152 + 512);
  float4 am0 = {0.f, 0.f, 0.f, 0.f};
  float4 am1 = {0.f, 0.f, 0.f, 0.f};
  float4 am2 = {0.f, 0.f, 0.f, 0.f};
  float4 am3 = {0.f, 0.f, 0.f, 0.f};
  float4 am4 = {0.f, 0.f, 0.f, 0.f};
  for (int w = 0; w < 32; ++w) {
    const float4 xa = X4[5 * w + 0];
    const float4 xb = X4[5 * w + 1];
    const float4 xc = X4[5 * w + 2];
    const float4 xd = X4[5 * w + 3];
    const float4 xe = X4[5 * w + 4];
    const float* Ab = A + w * 256 + o4;
    const float4 a0 = *(const float4*)(Ab);
    const float4 a1 = *(const float4*)(Ab + 64);
    const float4 a2 = *(const float4*)(Ab + 128);
    const float4 a3 = *(const float4*)(Ab + 192);
    am0 = fmaf4(a0, xa.x, am0); am1 = fmaf4(a0, xa.y, am1); am2 = fmaf4(a0, xa.z, am2);
    am3 = fmaf4(a0, xa.w, am3); am4 = fmaf4(a0, xb.x, am4);
    am0 = fmaf4(a1, xb.y, am0); am1 = fmaf4(a1, xb.z, am1); am2 = fmaf4(a1, xb.w, am2);
    am3 = fmaf4(a1, xc.x, am3); am4 = fmaf4(a1, xc.y, am4);
    am0 = fmaf4(a2, xc.z, am0); am1 = fmaf4(a2, xc.w, am1); am2 = fmaf4(a2, xd.x, am2);
    am3 = fmaf4(a2, xd.y, am3); am4 = fmaf4(a2, xd.z, am4);
    am0 = fmaf4(a3, xd.w, am0); am1 = fmaf4(a3, xe.x, am1); am2 = fmaf4(a3, xe.y, am2);
    am3 = fmaf4(a3, xe.z, am3); am4 = fmaf4(a3, xe.w, am4);
  }
  const bool isf = (n == gi);
#define EPI2(JJ, CMP)                                                          \
  {                                                                            \
    const int o = obase + o4 + JJ;                                             \
    const float c0v = am0.CMP * INVS;                                          \
    const float c1v = am1.CMP * INVS;                                          \
    const float c2v = am2.CMP * INVS;                                          \
    const float c3v = am3.CMP * INVS;                                          \
    const float c4v = am4.CMP * INVS;                                          \
    if (isf) {                                                                 \
      float* bp = scov + (size_t)g * 1152 + 512 + o * 5;                       \
      bp[0] = c0v; bp[1] = c1v; bp[2] = c2v; bp[3] = c3v; bp[4] = c4v;         \
    }                                                                          \
    sinv[(size_t)n * 384 + 256 + o] =                                          \
        sqrtf(1e-12f + c0v * c0v + c1v * c1v + c2v * c2v + c3v * c3v +         \
              c4v * c4v);                                                      \
  }
  EPI2(0, x) EPI2(1, y) EPI2(2, z) EPI2(3, w)
#undef EPI2
}

__global__ __launch_bounds__(320) void k_cov(
    const float* __restrict__ s_inter, const float* __restrict__ bag,
    const int* __restrict__ ptr, const int* __restrict__ focus,
    const float* __restrict__ W_bag,
    float* __restrict__ sinv, float* __restrict__ scov) {
  __shared__ __align__(16) float A[8192];  // 32 KB
  const int g = blockIdx.x;
  const int obase = blockIdx.y * 64;
  const int n0 = ptr[g];
  const int gi = n0 + focus[g];
  const float b0 = bag[g * 4 + 0], b1 = bag[g * 4 + 1];
  const float b2 = bag[g * 4 + 2], b3 = bag[g * 4 + 3];
  cov_l0(s_inter, W_bag, b0, b1, b2, b3, n0, gi, g, obase, sinv, scov, A);
  cov_l1(s_inter, W_bag + 65536, b0, b1, b2, b3, n0, gi, g, obase, sinv, scov, A);
  cov_l2(s_inter, W_bag + 131072, b0, b1, b2, b3, n0, gi, g, obase, sinv, scov, A);
}

// Kernel 2 v3: 16 nodes per 128-thread block; thread t = hidden unit t.
// W1f/W1e column scalars prefetched one 4-step ahead across the whole 384 loop.
__global__ __launch_bounds__(128) void k_mlp(
    const float* __restrict__ sinv, const float* __restrict__ bag,
    const int* __restrict__ batch, const int* __restrict__ element,
    const float* __restrict__ W1f, const float* __restrict__ b1f,
    const float* __restrict__ W2f, const float* __restrict__ b2f,
    const float* __restrict__ W1e, const float* __restrict__ b1e,
    const float* __restrict__ W2e, const float* __restrict__ b2e,
    float* __restrict__ flv, float* __restrict__ helv, float* __restrict__ lpelv) {
  __shared__ __align__(16) float lds[4224];  // chunk: [16][64]; later hf/he [16][132] x2
  __shared__ float els[16][4];
  const int t = threadIdx.x;
  const int n0 = blockIdx.x * 16;
  float af[16], ae[16];
#pragma unroll
  for (int p = 0; p < 16; ++p) { af[p] = 0.f; ae[p] = 0.f; }
  const float bf = b1f[t], be = b1e[t];
  float wfc[4], wec[4], wfn[4], wen[4];
#pragma unroll
  for (int j = 0; j < 4; ++j) {
    wfc[j] = W1f[j * 128 + t];
    wec[j] = W1e[j * 128 + t];
  }
  for (int cb = 0; cb < 6; ++cb) {
    const int c0 = cb * 64;
    __syncthreads();
    {
      const int p = t >> 3, q = (t & 7) * 8;
      const float* src = sinv + (size_t)(n0 + p) * 384 + c0 + q;
      const float4 v0 = *(const float4*)(src);
      const float4 v1 = *(const float4*)(src + 4);
      *(float4*)(lds + p * 64 + q) = v0;
      *(float4*)(lds + p * 64 + q + 4) = v1;
    }
    __syncthreads();
    for (int cc = 0; cc < 64; cc += 4) {
      const int cnext = c0 + cc + 4;
      const int cpf = (cnext < 384) ? cnext : 380;
#pragma unroll
      for (int j = 0; j < 4; ++j) {
        wfn[j] = W1f[(cpf + j) * 128 + t];
        wen[j] = W1e[(cpf + j) * 128 + t];
      }
#pragma unroll
      for (int p = 0; p < 16; ++p) {
        const float4 s4 = *(const float4*)(lds + p * 64 + cc);
        af[p] = fmaf(s4.x, wfc[0], af[p]);
        af[p] = fmaf(s4.y, wfc[1], af[p]);
        af[p] = fmaf(s4.z, wfc[2], af[p]);
        af[p] = fmaf(s4.w, wfc[3], af[p]);
        ae[p] = fmaf(s4.x, wec[0], ae[p]);
        ae[p] = fmaf(s4.y, wec[1], ae[p]);
        ae[p] = fmaf(s4.z, wec[2], ae[p]);
        ae[p] = fmaf(s4.w, wec[3], ae[p]);
      }
#pragma unroll
      for (int j = 0; j < 4; ++j) { wfc[j] = wfn[j]; wec[j] = wen[j]; }
    }
  }
  __syncthreads();
#pragma unroll
  for (int p = 0; p < 16; ++p) {
    lds[p * 132 + t] = fmaxf(af[p] + bf, 0.f);          // hf
    lds[2112 + p * 132 + t] = fmaxf(ae[p] + be, 0.f);   // he
  }
  __syncthreads();
  if (t < 80) {  // 16 nodes x (1 fl + 4 el)
    const int p = t / 5, q = t - p * 5;
    if (q == 0) {
      float s = 0.f;
      for (int j = 0; j < 128; ++j) s = fmaf(lds[p * 132 + j], W2f[j], s);
      flv[n0 + p] = s + b2f[0];
    } else {
      const int z = q - 1;
      float s = 0.f;
      for (int j = 0; j < 128; ++j) s = fmaf(lds[2112 + p * 132 + j], W2e[j * 4 + z], s);
      els[p][z] = s + b2e[z];
    }
  }
  __syncthreads();
  if (t < 16) {
    const int n = n0 + t;
    const int g = batch[n];
    const int elem = element[g];
    float v[4];
#pragma unroll
    for (int z = 0; z < 4; ++z) {
      const bool mk = bag[g * 4 + z] > 0.f;
      v[z] = mk ? els[t][z] : -1e9f;
    }
    const float mx = fmaxf(fmaxf(v[0], v[1]), fmaxf(v[2], v[3]));
    float e[4];
    float S = 0.f;
#pragma unroll
    for (int z = 0; z < 4; ++z) { e[z] = expf(v[z] - mx); S += e[z]; }
    const float iS = 1.f / S;
    float h = 0.f;
#pragma unroll
    for (int z = 0; z < 4; ++z) {
      const float pz = e[z] * iS;
      h -= pz * logf(fmaxf(pz, 1e-20f));
    }
    helv[n] = h;
    lpelv[n] = logf(e[elem] * iS + 1e-20f);
  }
}

// Kernel 3: per-group epilogue.
__global__ __launch_bounds__(128) void k_group(
    const int* __restrict__ ptr, const int* __restrict__ focus,
    const int* __restrict__ element, const float* __restrict__ distance,
    const float* __restrict__ orientation, const float* __restrict__ dls,
    const float* __restrict__ W_mix,
    const float* __restrict__ W1d, const float* __restrict__ b1d,
    const float* __restrict__ W2d, const float* __restrict__ b2d,
    const float* __restrict__ flv, const float* __restrict__ helv,
    const float* __restrict__ lpelv, const float* __restrict__ sinv,
    const float* __restrict__ scov, const float* __restrict__ yg,
    float* __restrict__ out) {
  __shared__ float fls[32];
  __shared__ float hels[32];
  __shared__ __align__(16) float svg[384];
  __shared__ float hd[128];
  __shared__ float out6[6];
  __shared__ float red[128][12];
  __shared__ float conds[9];
  __shared__ float mred[128];
  __shared__ float sred[128];
  const int g = blockIdx.x;
  const int t = threadIdx.x;
  const int n0 = ptr[g];
  const int nseg = ptr[g + 1] - n0;
  const int floc = focus[g];
  const int gi = n0 + floc;
  const int elem = element[g];
  const float dist = distance[g];
  if (t < nseg) { fls[t] = flv[n0 + t]; hels[t] = helv[n0 + t]; }
  for (int c = t; c < 384; c += 128) svg[c] = sinv[(size_t)gi * 384 + c];
  __syncthreads();
  float res_lpf = 0.f, res_ent = 0.f;
  if (t == 0) {  // focus softmax + entropies (20-long serial)
    float mx = -1e30f;
    for (int p = 0; p < nseg; ++p) mx = fmaxf(mx, fls[p]);
    float S = 0.f;
    for (int p = 0; p < nseg; ++p) S += expf(fls[p] - mx);
    const float iS = 1.f / S;
    float hfoc = 0.f, hef = 0.f;
    for (int p = 0; p < nseg; ++p) {
      const float pp = expf(fls[p] - mx) * iS;
      hfoc -= pp * logf(pp + 1e-20f);
      hef += pp * hels[p];
    }
    res_lpf = logf(expf(fls[floc] - mx) * iS + 1e-20f);
    res_ent = hfoc + hef;
  }
  // d-MLP hidden: thread t = hidden unit
  {
    float acc = b1d[t];
    for (int c = 0; c < 384; c += 4) {
      const float4 s4 = *(const float4*)(&svg[c]);
      acc = fmaf(s4.x, W1d[(c + 0) * 128 + t], acc);
      acc = fmaf(s4.y, W1d[(c + 1) * 128 + t], acc);
      acc = fmaf(s4.z, W1d[(c + 2) * 128 + t], acc);
      acc = fmaf(s4.w, W1d[(c + 3) * 128 + t], acc);
    }
    acc += W1d[(384 + elem) * 128 + t];  // one-hot element tail
    hd[t] = fmaxf(acc, 0.f);
  }
  __syncthreads();
  if (t < 6) {
    float s = 0.f;
    for (int j = 0; j < 128; ++j) s = fmaf(hd[j], W2d[j * 6 + t], s);
    out6[t] = s + b2d[t];
  }
  // Bessel mix + conditional cov partials (thread t = i index)
  {
    float bess[8];
    const float sq2d = 1.0540925533894598f;  // sqrt(2/1.8)
#pragma unroll
    for (int k = 0; k < 8; ++k)
      bess[k] = sq2d * sinf((float)(k + 1) * 3.14159265358979323846f * dist / 1.8f) / dist;
    const float invnb = 0.35355339059327373f;  // 1/sqrt(8)
    float partial[9];
    {
      float tw = 0.f;
#pragma unroll
      for (int k = 0; k < 8; ++k) tw += bess[k] * W_mix[k * 1536 + t * 4 + elem];
      tw *= invnb;
      partial[0] = scov[(size_t)g * 1152 + t] * tw;
    }
    {
      float tw = 0.f;
#pragma unroll
      for (int k = 0; k < 8; ++k) tw += bess[k] * W_mix[k * 1536 + (128 + t) * 4 + elem];
      tw *= invnb;
#pragma unroll
      for (int m = 0; m < 3; ++m) partial[1 + m] = scov[(size_t)g * 1152 + 128 + t * 3 + m] * tw;
    }
    {
      float tw = 0.f;
#pragma unroll
      for (int k = 0; k < 8; ++k) tw += bess[k] * W_mix[k * 1536 + (256 + t) * 4 + elem];
      tw *= invnb;
#pragma unroll
      for (int m = 0; m < 5; ++m) partial[4 + m] = scov[(size_t)g * 1152 + 512 + t * 5 + m] * tw;
    }
#pragma unroll
    for (int q = 0; q < 9; ++q) red[t][q] = partial[q];
  }
  __syncthreads();
  if (t < 9) {
    float s = 0.f;
    for (int i = 0; i < 128; ++i) s += red[i][t];
    conds[t] = s * 0.044194173824159216f;  // /sqrt(512)
  }
  __syncthreads();
  const float c0 = conds[0], c1 = conds[1], c2 = conds[2], c3 = conds[3];
  const float c4 = conds[4], c5 = conds[5], c6 = conds[6], c7 = conds[7];
  const float c8 = conds[8];
  // spherical logsumexp over 4096 grid points (online per thread)
  float lm = -1e30f, ls = 0.f;
  for (int p = t; p < 4096; p += 128) {
    const float* yp = yg + p * 9;
    float v = c0 * yp[0] + c1 * yp[1] + c2 * yp[2] + c3 * yp[3] + c4 * yp[4] +
              c5 * yp[5] + c6 * yp[6] + c7 * yp[7] + c8 * yp[8];
    v *= 10.0f;
    if (v > lm) { ls = ls * expf(lm - v) + 1.f; lm = v; }
    else ls += expf(v - lm);
  }
  mred[t] = lm;
  sred[t] = ls;
  __syncthreads();
  if (t == 0) {
    // distance GMM
    const float l0 = out6[0], l1 = out6[1], l2 = out6[2];
    const float lmx = fmaxf(l0, fmaxf(l1, l2));
    const float lsew = lmx + logf(expf(l0 - lmx) + expf(l1 - lmx) + expf(l2 - lmx));
    float vals[3];
#pragma unroll
    for (int k = 0; k < 3; ++k) {
      const float mean = tanhf(out6[3 + k]) * 0.45f + 1.35f;
      const float sd = fmaxf(expf(dls[k]), 1e-6f);
      const float zz = (dist - mean) / sd;
      vals[k] = (out6[k] - lsew) + (-0.5f * zz * zz - logf(sd) - 0.9189385332046727f);
    }
    const float vm = fmaxf(vals[0], fmaxf(vals[1], vals[2]));
    const float lp_dist =
        vm + logf(expf(vals[0] - vm) + expf(vals[1] - vm) + expf(vals[2] - vm));
    // merge grid lse
    float Mx = -1e30f;
    for (int i = 0; i < 128; ++i) Mx = fmaxf(Mx, mred[i]);
    float S = 0.f;
    for (int i = 0; i < 128; ++i) S += sred[i] * expf(mred[i] - Mx);
    const float logZ = Mx + logf(S) - 8.317766166719343f + 2.5310242469692907f;
    // orientation term
    float ox = orientation[g * 3 + 0], oy = orientation[g * 3 + 1], oz = orientation[g * 3 + 2];
    const float inr = 1.f / sqrtf(ox * ox + oy * oy + oz * oz);
    ox *= inr; oy *= inr; oz *= inr;
    float sh[9];
    real_sh9(ox, oy, oz, sh);
    const float fx = c0 * sh[0] + c1 * sh[1] + c2 * sh[2] + c3 * sh[3] + c4 * sh[4] +
                     c5 * sh[5] + c6 * sh[6] + c7 * sh[7] + c8 * sh[8];
    const float lp_ori = 10.0f * fx - logZ;
    out[g * 2 + 0] = res_lpf + lpelv[gi] + lp_dist + lp_ori;
    out[g * 2 + 1] = res_ent;
  }
}

extern "C" void kernel_launch(void* const* d_in, const int* in_sizes, int n_in,
                              void* d_out, int out_size, void* d_ws, size_t ws_size,
                              hipStream_t stream) {
  const float* s_inter = (const float*)d_in[0];
  const float* bag = (const float*)d_in[1];
  const int* batch = (const int*)d_in[2];
  const int* ptr = (const int*)d_in[3];
  const int* focus = (const int*)d_in[4];
  const int* element = (const int*)d_in[5];
  const float* distance = (const float*)d_in[6];
  const float* orientation = (const float*)d_in[7];
  const float* W_bag = (const float*)d_in[8];
  const float* dls = (const float*)d_in[9];
  const float* W_mix = (const float*)d_in[10];
  const float* W1f = (const float*)d_in[11];
  const float* b1f = (const float*)d_in[12];
  const float* W2f = (const float*)d_in[13];
  const float* b2f = (const float*)d_in[14];
  const float* W1e = (const float*)d_in[15];
  const float* b1e = (const float*)d_in[16];
  const float* W2e = (const float*)d_in[17];
  const float* b2e = (const float*)d_in[18];
  const float* W1d = (const float*)d_in[19];
  const float* b1d = (const float*)d_in[20];
  const float* W2d = (const float*)d_in[21];
  const float* b2d = (const float*)d_in[22];

  if (ws_size < (size_t)WS_TOTAL * sizeof(float)) return;  // need ~89 MB scratch

  float* ws = (float*)d_ws;
  float* yg = ws + WS_YG;
  float* sinv = ws + WS_SINV;
  float* flv = ws + WS_FL;
  float* helv = ws + WS_HEL;
  float* lpelv = ws + WS_LPEL;
  float* scov = ws + WS_SCOV;
  float* out = (float*)d_out;

  k_ygrid<<<dim3(32), dim3(128), 0, stream>>>(yg);
  k_cov<<<dim3(GG, 2), dim3(320), 0, stream>>>(s_inter, bag, ptr, focus, W_bag, sinv, scov);
  k_mlp<<<dim3(NN / 16), dim3(128), 0, stream>>>(sinv, bag, batch, element,
                                                 W1f, b1f, W2f, b2f,
                                                 W1e, b1e, W2e, b2e,
                                                 flv, helv, lpelv);
  k_group<<<dim3(GG), dim3(128), 0, stream>>>(ptr, focus, element, distance, orientation,
                                              dls, W_mix, W1d, b1d, W2d, b2d,
                                              flv, helv, lpelv, sinv, scov, yg, out);
}